// Round 7
// baseline (6338.878 us; speedup 1.0000x reference)
//
#include <hip/hip_runtime.h>

// B=256, T=512, I=128, H=256, 4H=1024
// 64 blocks = 4 row-groups (64 batch rows) x 16 col-groups (16 hidden units).
// DATA-AS-FLAG protocol: h stored as tagged words (bf16<<16 | step_tag) via sc0 sc1
// dword stores (atomic per word). Readers poll-load their fragment until every tag
// equals the step number. No flags, no store drains, no counted vmcnt -> the three
// serial fabric RTs of round 4 collapse into ~one. Double-buffer is sufficient:
// validating h_s proves all reads of h_{s-1} are complete (same induction as r4).
// Replay-safe: zero_kernel (in-graph) re-tags buf0=tag0 (h0=0), buf1=0xFFFF sentinel.

typedef __bf16 bf16;
typedef bf16 bf16x8 __attribute__((ext_vector_type(8)));
typedef float f32x4 __attribute__((ext_vector_type(4)));
typedef unsigned u32;
typedef u32 u32x4 __attribute__((ext_vector_type(4)));

#define MFMA16(a, b, c) __builtin_amdgcn_mfma_f32_16x16x32_bf16((a), (b), (c), 0, 0, 0)
#define AT_STORE_DEV(p, v) __hip_atomic_store((p), (v), __ATOMIC_RELAXED, __HIP_MEMORY_SCOPE_AGENT)

__device__ __forceinline__ float sigm(float x) { return 1.0f / (1.0f + __expf(-x)); }
__device__ __forceinline__ float tanhfast(float x) { return 1.0f - 2.0f / (__expf(2.0f * x) + 1.0f); }

// device-coherent tagged-word ops (L1+L2 bypass; round-4-proven path)
#define GLD4(dst, addr, OFF) \
    asm volatile("global_load_dwordx4 %0, %1, off offset:" OFF " sc0 sc1" \
                 : "=v"(dst) : "v"(addr))
#define GST1(addr, val, OFF) \
    asm volatile("global_store_dword %0, %1, off offset:" OFF " sc0 sc1" \
                 :: "v"(addr), "v"(val) : "memory")

// issue all 16 fragment loads (8 tiles x 2 dwordx4); byte offsets ks*128 + {0,16}
#define ISSUE_ALL(hb)                                   \
    GLD4(La[0], hb, "0");   GLD4(Lb[0], hb, "16");      \
    GLD4(La[1], hb, "128"); GLD4(Lb[1], hb, "144");     \
    GLD4(La[2], hb, "256"); GLD4(Lb[2], hb, "272");     \
    GLD4(La[3], hb, "384"); GLD4(Lb[3], hb, "400");     \
    GLD4(La[4], hb, "512"); GLD4(Lb[4], hb, "528");     \
    GLD4(La[5], hb, "640"); GLD4(Lb[5], hb, "656");     \
    GLD4(La[6], hb, "768"); GLD4(Lb[6], hb, "784");     \
    GLD4(La[7], hb, "896"); GLD4(Lb[7], hb, "912")

// poll until every tag (low16 of all 32 words) == rtag; bounded spin -> fast fail
#define POLL_FRESH(hb, rtag)                                                     \
    {                                                                            \
        int spins = 0;                                                           \
        for (;;) {                                                               \
            asm volatile("s_waitcnt vmcnt(0)" ::: "memory");                     \
            __builtin_amdgcn_sched_barrier(0);                                   \
            u32 err = 0;                                                         \
            _Pragma("unroll")                                                    \
            for (int ks = 0; ks < 8; ks++) {                                     \
                err |= (La[ks].x ^ (rtag)); err |= (La[ks].y ^ (rtag));          \
                err |= (La[ks].z ^ (rtag)); err |= (La[ks].w ^ (rtag));          \
                err |= (Lb[ks].x ^ (rtag)); err |= (Lb[ks].y ^ (rtag));          \
                err |= (Lb[ks].z ^ (rtag)); err |= (Lb[ks].w ^ (rtag));          \
            }                                                                    \
            if (__all((int)((err & 0xFFFFu) == 0u))) break;                      \
            if (++spins > 16384) break;                                          \
            __builtin_amdgcn_s_sleep(2);                                         \
            ISSUE_ALL(hb);                                                       \
        }                                                                        \
        __builtin_amdgcn_sched_barrier(0);                                       \
    }

// unpack tile ks: high halves of 8 tagged words -> bf16x8 A-fragment
#define UNPK(ks)                                                                 \
    {                                                                            \
        u32x4 v;                                                                 \
        v.x = __builtin_amdgcn_perm(La[ks].y, La[ks].x, 0x07060302u);            \
        v.y = __builtin_amdgcn_perm(La[ks].w, La[ks].z, 0x07060302u);            \
        v.z = __builtin_amdgcn_perm(Lb[ks].y, Lb[ks].x, 0x07060302u);            \
        v.w = __builtin_amdgcn_perm(Lb[ks].w, Lb[ks].z, 0x07060302u);            \
        ha[ks] = __builtin_bit_cast(bf16x8, v);                                  \
    }

// ---------------- weight packing (fragment layout, unchanged) ----------------
__global__ void pack_kernel(const float* __restrict__ eWih, const float* __restrict__ eWhh,
                            const float* __restrict__ dWih, const float* __restrict__ dWhh,
                            const float* __restrict__ linW,
                            bf16* __restrict__ encB, bf16* __restrict__ decB, bf16* __restrict__ linB) {
    int idx = blockIdx.x * 256 + threadIdx.x;  // 0 .. 819199
    if (idx < 786432) {
        int which = idx / 393216;          // 0 = enc, 1 = dec
        int id = idx % 393216;
        int cg = id / 24576;
        int rem = id % 24576;
        int ks = rem / 2048;
        int n = (rem / 512) & 3;
        int lane = (rem >> 3) & 63;
        int e = rem & 7;
        int k = ks * 32 + (lane >> 4) * 8 + e;
        int col = n * 256 + cg * 16 + (lane & 15);
        const float* Wih = which ? dWih : eWih;
        const float* Whh = which ? dWhh : eWhh;
        float v = (k < 128) ? Wih[col * 128 + k] : Whh[col * 256 + (k - 128)];
        (which ? decB : encB)[id] = (bf16)v;
    } else if (idx < 819200) {
        int i3 = idx - 786432;             // 0 .. 32767
        int ks = i3 >> 12;
        int n = (i3 >> 9) & 7;
        int lane = (i3 >> 3) & 63;
        int e = i3 & 7;
        int k = ks * 32 + (lane >> 4) * 8 + e;
        int col = n * 16 + (lane & 15);
        linB[i3] = (bf16)linW[col * 256 + k];
    }
}

// re-tag both h phases every launch (replay safety; runs inside the graph)
__global__ void zero_kernel(unsigned* __restrict__ p) {
    int i = blockIdx.x * 256 + threadIdx.x;
    if (i < 65536) AT_STORE_DEV(&p[i], 0u);                 // buf0: h0=0, tag 0 (valid)
    else if (i < 131072) AT_STORE_DEV(&p[i], 0x0000FFFFu);  // buf1: sentinel tag
}

// ---------------- main persistent kernel ----------------
__global__ __launch_bounds__(256, 1)
void lstm_main(const float* __restrict__ x,
               const float* __restrict__ eb_ih, const float* __restrict__ eb_hh,
               const float* __restrict__ db_ih, const float* __restrict__ db_hh,
               const float* __restrict__ lin_b,
               const bf16* __restrict__ encB, const bf16* __restrict__ decB,
               const bf16* __restrict__ linB,
               u32* __restrict__ hbuf32,
               float* __restrict__ out) {
    __shared__ bf16 Bg[24576];         // 48 KB gate-weight fragments (this cg)
    __shared__ bf16 Lw[32768];         // 64 KB lin_W fragments (decoder)
    __shared__ bf16 Pst[4 * 16 * 136]; // 17 KB pred staging, per-wave, pitch 136

    const int bid = blockIdx.x;
    const int rg = bid >> 4;           // row-group 0..3  (64 batch rows)
    const int cg = bid & 15;           // col-group 0..15 (16 hidden units)
    const int tid = threadIdx.x;
    const int w = tid >> 6;
    const int lane = tid & 63;
    const int l15 = lane & 15, l4 = lane >> 4;
    const int rbase = rg * 64 + w * 16;       // wave's 16 batch rows
    const int ucol = cg * 16 + l15;           // this lane's hidden unit
    const int arow = rbase + l15;             // A-fragment row this lane loads
    const int k0 = l4 * 8;                    // A-fragment k sub-offset
    const int prow = rbase + l4 * 4;          // epilogue row base

    // tagged h layout: hbuf[phase 65536][rt=16][row16=16][unit=256] (1 word/bf16)
    const int rt = rg * 4 + w;                           // this wave's row tile
    const int rd_off = rt * 4096 + l15 * 256 + l4 * 8;   // reader base (word)
    const int wr_off = rt * 4096 + (l4 * 4) * 256 + ucol;// writer base (word, +r*256)

    // load encoder gate weights into LDS
    {
        const f32x4* src = (const f32x4*)(encB + cg * 24576);
        f32x4* dst = (f32x4*)Bg;
        #pragma unroll
        for (int i = 0; i < 12; i++) dst[tid + 256 * i] = src[tid + 256 * i];
    }
    float bias_g[4];
    #pragma unroll
    for (int g = 0; g < 4; g++) bias_g[g] = eb_ih[g * 256 + ucol] + eb_hh[g * 256 + ucol];
    __syncthreads();

    float c[4] = {0.f, 0.f, 0.f, 0.f};
    const float* xrow = x + (size_t)arow * 512 * 128 + k0;  // x[arow][t][k0+..]

    // preload x fragments for t=0
    f32x4 xr[8];
    #pragma unroll
    for (int i = 0; i < 4; i++) {
        xr[2 * i]     = *(const f32x4*)(xrow + i * 32);
        xr[2 * i + 1] = *(const f32x4*)(xrow + i * 32 + 4);
    }

    // =================== encoder: 512 steps ===================
    for (int t = 0; t < 512; t++) {
        const u32* hb = hbuf32 + (t & 1) * 65536 + rd_off;
        u32* hw32 = hbuf32 + ((t + 1) & 1) * 65536;
        const u32 rtag = (u32)t;

        u32x4 La[8], Lb[8];
        ISSUE_ALL(hb);

        f32x4 acc[4];
        #pragma unroll
        for (int n = 0; n < 4; n++) acc[n] = (f32x4){0.f, 0.f, 0.f, 0.f};

        // x part (K 0..127) from prefetched regs — may overlap h-load flight
        #pragma unroll
        for (int ks = 0; ks < 4; ks++) {
            f32x4 xa = xr[2 * ks], xb = xr[2 * ks + 1];
            bf16x8 a;
            a[0] = (bf16)xa[0]; a[1] = (bf16)xa[1]; a[2] = (bf16)xa[2]; a[3] = (bf16)xa[3];
            a[4] = (bf16)xb[0]; a[5] = (bf16)xb[1]; a[6] = (bf16)xb[2]; a[7] = (bf16)xb[3];
            #pragma unroll
            for (int n = 0; n < 4; n++) {
                bf16x8 b = *(const bf16x8*)&Bg[((ks * 4 + n) * 64 + lane) * 8];
                acc[n] = MFMA16(a, b, acc[n]);
            }
        }
        // poll until this step's tags are fresh, then unpack + h part (K 128..383)
        POLL_FRESH(hb, rtag);
        bf16x8 ha[8];
        #pragma unroll
        for (int ks = 0; ks < 8; ks++) {
            UNPK(ks);
            #pragma unroll
            for (int n = 0; n < 4; n++) {
                bf16x8 b = *(const bf16x8*)&Bg[(((ks + 4) * 4 + n) * 64 + lane) * 8];
                acc[n] = MFMA16(ha[ks], b, acc[n]);
            }
        }
        // epilogue: lane owns rows prow+r, unit ucol; tagged fire-and-forget stores
        const u32 wtag = (u32)(t + 1);
        u32 tv[4];
        #pragma unroll
        for (int r = 0; r < 4; r++) {
            float gi = sigm(acc[0][r] + bias_g[0]);
            float gf = sigm(acc[1][r] + bias_g[1]);
            float gg = tanhfast(acc[2][r] + bias_g[2]);
            float go = sigm(acc[3][r] + bias_g[3]);
            c[r] = gf * c[r] + gi * gg;
            float h = go * tanhfast(c[r]);
            tv[r] = ((u32)__builtin_bit_cast(unsigned short, (bf16)h) << 16) | wtag;
        }
        u32* wb = hw32 + wr_off;
        GST1(wb, tv[0], "0");
        GST1(wb, tv[1], "1024");
        GST1(wb, tv[2], "2048");
        GST1(wb, tv[3], "3072");
        // prefetch x for next step (completes under next poll)
        int tn = t < 511 ? t + 1 : 511;
        #pragma unroll
        for (int i = 0; i < 4; i++) {
            xr[2 * i]     = *(const f32x4*)(xrow + (size_t)tn * 128 + i * 32);
            xr[2 * i + 1] = *(const f32x4*)(xrow + (size_t)tn * 128 + i * 32 + 4);
        }
    }

    // =================== switch to decoder weights ===================
    __syncthreads();   // all 4 waves exited encoder (each validated h_512) -> Bg free
    {
        const f32x4* src = (const f32x4*)(decB + cg * 24576);
        f32x4* dst = (f32x4*)Bg;
        #pragma unroll
        for (int i = 0; i < 12; i++) dst[tid + 256 * i] = src[tid + 256 * i];
        const f32x4* s2 = (const f32x4*)linB;
        f32x4* d2 = (f32x4*)Lw;
        #pragma unroll
        for (int i = 0; i < 16; i++) d2[tid + 256 * i] = s2[tid + 256 * i];
    }
    float bias_d[4];
    #pragma unroll
    for (int g = 0; g < 4; g++) bias_d[g] = db_ih[g * 256 + ucol] + db_hh[g * 256 + ucol];
    float lbias[8];
    #pragma unroll
    for (int n = 0; n < 8; n++) lbias[n] = lin_b[n * 16 + l15];
    __syncthreads();

    const int ncg = cg >> 1;   // out columns this block writes: n == ncg, half == (cg&1)
    const int hsel = cg & 1;

    // =================== decoder: pred(k) then gates(k) ===================
    for (int k = 0; k < 512; k++) {
        const u32* hb = hbuf32 + (k & 1) * 65536 + rd_off;
        const u32 rtag = (u32)(512 + k);

        u32x4 La[8], Lb[8];
        ISSUE_ALL(hb);
        POLL_FRESH(hb, rtag);
        bf16x8 ha[8];
        #pragma unroll
        for (int ks = 0; ks < 8; ks++) UNPK(ks);

        // pred = sigmoid(h @ lin_W^T + lin_b)  [64 x 128], redundant per block
        f32x4 pacc[8];
        #pragma unroll
        for (int n = 0; n < 8; n++) pacc[n] = (f32x4){0.f, 0.f, 0.f, 0.f};
        #pragma unroll
        for (int ks = 0; ks < 8; ks++) {
            #pragma unroll
            for (int n = 0; n < 8; n++) {
                bf16x8 b = *(const bf16x8*)&Lw[((ks * 8 + n) * 64 + lane) * 8];
                pacc[n] = MFMA16(ha[ks], b, pacc[n]);
            }
        }
        const int t_out = 511 - k;
        float* obase = out + (size_t)prow * 512 * 128 + (size_t)t_out * 128;
        bf16* pst_w = Pst + w * 2176;
        #pragma unroll
        for (int n = 0; n < 8; n++) {
            #pragma unroll
            for (int r = 0; r < 4; r++) {
                float p = sigm(pacc[n][r] + lbias[n]);
                pst_w[(l4 * 4 + r) * 136 + n * 16 + l15] = (bf16)p;
                if (n == ncg && (l15 >> 3) == hsel)
                    obase[(size_t)r * 512 * 128 + n * 16 + l15] = p;
            }
        }
        if (k == 511) break;  // last step: prediction only

        // gates = [pred | h] @ Wdec^T
        f32x4 acc[4];
        #pragma unroll
        for (int n = 0; n < 4; n++) acc[n] = (f32x4){0.f, 0.f, 0.f, 0.f};
        #pragma unroll
        for (int ks = 0; ks < 8; ks++) {
            #pragma unroll
            for (int n = 0; n < 4; n++) {
                bf16x8 b = *(const bf16x8*)&Bg[(((ks + 4) * 4 + n) * 64 + lane) * 8];
                acc[n] = MFMA16(ha[ks], b, acc[n]);
            }
        }
        const bf16* pst_r = Pst + w * 2176 + l15 * 136 + k0;
        #pragma unroll
        for (int ks = 0; ks < 4; ks++) {
            bf16x8 a = *(const bf16x8*)(pst_r + ks * 32);
            #pragma unroll
            for (int n = 0; n < 4; n++) {
                bf16x8 b = *(const bf16x8*)&Bg[((ks * 4 + n) * 64 + lane) * 8];
                acc[n] = MFMA16(a, b, acc[n]);
            }
        }
        // epilogue: tagged h stores (tag 513+k)
        u32* hw32 = hbuf32 + ((k + 1) & 1) * 65536;
        const u32 wtag = (u32)(513 + k);
        u32 tv[4];
        #pragma unroll
        for (int r = 0; r < 4; r++) {
            float gi = sigm(acc[0][r] + bias_d[0]);
            float gf = sigm(acc[1][r] + bias_d[1]);
            float gg = tanhfast(acc[2][r] + bias_d[2]);
            float go = sigm(acc[3][r] + bias_d[3]);
            c[r] = gf * c[r] + gi * gg;
            float h = go * tanhfast(c[r]);
            tv[r] = ((u32)__builtin_bit_cast(unsigned short, (bf16)h) << 16) | wtag;
        }
        u32* wb = hw32 + wr_off;
        GST1(wb, tv[0], "0");
        GST1(wb, tv[1], "1024");
        GST1(wb, tv[2], "2048");
        GST1(wb, tv[3], "3072");
    }
}

extern "C" void kernel_launch(void* const* d_in, const int* in_sizes, int n_in,
                              void* d_out, int out_size, void* d_ws, size_t ws_size,
                              hipStream_t stream) {
    const float* x    = (const float*)d_in[0];
    const float* eWih = (const float*)d_in[1];
    const float* eWhh = (const float*)d_in[2];
    const float* ebih = (const float*)d_in[3];
    const float* ebhh = (const float*)d_in[4];
    const float* dWih = (const float*)d_in[5];
    const float* dWhh = (const float*)d_in[6];
    const float* dbih = (const float*)d_in[7];
    const float* dbhh = (const float*)d_in[8];
    const float* linW = (const float*)d_in[9];
    const float* linb = (const float*)d_in[10];
    float* out = (float*)d_out;

    // workspace layout (~2.1 MB)
    bf16* encB = (bf16*)d_ws;            // 393216 bf16
    bf16* decB = encB + 393216;          // 393216 bf16
    bf16* linB = decB + 393216;          // 32768 bf16
    u32*  hbuf = (u32*)(linB + 32768);   // 2 x 16 tiles x 16 rows x 256 tagged words

    hipLaunchKernelGGL(pack_kernel, dim3(3200), dim3(256), 0, stream,
                       eWih, eWhh, dWih, dWhh, linW, encB, decB, linB);
    hipLaunchKernelGGL(zero_kernel, dim3(512), dim3(256), 0, stream, hbuf);
    hipLaunchKernelGGL(lstm_main, dim3(64), dim3(256), 0, stream,
                       x, ebih, ebhh, dbih, dbhh, linb, encB, decB, linB, hbuf, out);
}

// Round 8
// 6160.579 us; speedup vs baseline: 1.0289x; 1.0289x over previous
//
#include <hip/hip_runtime.h>

// B=256, T=512, I=128, H=256, 4H=1024
// 64 blocks = 4 row-groups x 16 col-groups. Hybrid protocol:
//   - h stored as tagged words (bf16<<16 | step) fire-and-forget (no store drain)
//   - per-WAVE flag lines posted fire-and-forget right after h stores
//   - readers: gate on flag poll (cheap, 1 word/lane), then load data once and
//     VALIDATE tags; retry only on rare fabric reorder (bounded)
// Per-wave chains: wave w of block (rg,cg) syncs only with wave w of peers
// (vmcnt is per-wave). No in-loop __syncthreads. All pieces proven in r4/r7.

typedef __bf16 bf16;
typedef bf16 bf16x8 __attribute__((ext_vector_type(8)));
typedef float f32x4 __attribute__((ext_vector_type(4)));
typedef unsigned u32;
typedef u32 u32x4 __attribute__((ext_vector_type(4)));

#define MFMA16(a, b, c) __builtin_amdgcn_mfma_f32_16x16x32_bf16((a), (b), (c), 0, 0, 0)
#define AT_STORE_DEV(p, v) __hip_atomic_store((p), (v), __ATOMIC_RELAXED, __HIP_MEMORY_SCOPE_AGENT)

__device__ __forceinline__ float sigm(float x) { return 1.0f / (1.0f + __expf(-x)); }
__device__ __forceinline__ float tanhfast(float x) { return 1.0f - 2.0f / (__expf(2.0f * x) + 1.0f); }

// device-coherent ops (L1+L2 bypass) — r4/r7-proven paths
#define GLD4(dst, addr, OFF) \
    asm volatile("global_load_dwordx4 %0, %1, off offset:" OFF " sc0 sc1" \
                 : "=v"(dst) : "v"(addr))
#define GST1(addr, val, OFF) \
    asm volatile("global_store_dword %0, %1, off offset:" OFF " sc0 sc1" \
                 :: "v"(addr), "v"(val) : "memory")
__device__ __forceinline__ u32 load_flag(const u32* p) {
    u32 v;
    asm volatile("global_load_dword %0, %1, off sc0 sc1\n\ts_waitcnt vmcnt(0)"
                 : "=v"(v) : "v"(p) : "memory");
    return v;
}

// issue all 16 fragment loads (8 tiles x 2 dwordx4); byte offsets ks*128 + {0,16}
#define ISSUE_ALL(hb)                                   \
    GLD4(La[0], hb, "0");   GLD4(Lb[0], hb, "16");      \
    GLD4(La[1], hb, "128"); GLD4(Lb[1], hb, "144");     \
    GLD4(La[2], hb, "256"); GLD4(Lb[2], hb, "272");     \
    GLD4(La[3], hb, "384"); GLD4(Lb[3], hb, "400");     \
    GLD4(La[4], hb, "512"); GLD4(Lb[4], hb, "528");     \
    GLD4(La[5], hb, "640"); GLD4(Lb[5], hb, "656");     \
    GLD4(La[6], hb, "768"); GLD4(Lb[6], hb, "784");     \
    GLD4(La[7], hb, "896"); GLD4(Lb[7], hb, "912")

// wait + tag-validate; retry (rare — flag gate precedes) bounded
#define POLL_FRESH(hb, rtag)                                                     \
    {                                                                            \
        int spins = 0;                                                           \
        for (;;) {                                                               \
            asm volatile("s_waitcnt vmcnt(0)" ::: "memory");                     \
            __builtin_amdgcn_sched_barrier(0);                                   \
            u32 err = 0;                                                         \
            _Pragma("unroll")                                                    \
            for (int ks = 0; ks < 8; ks++) {                                     \
                err |= (La[ks].x ^ (rtag)); err |= (La[ks].y ^ (rtag));          \
                err |= (La[ks].z ^ (rtag)); err |= (La[ks].w ^ (rtag));          \
                err |= (Lb[ks].x ^ (rtag)); err |= (Lb[ks].y ^ (rtag));          \
                err |= (Lb[ks].z ^ (rtag)); err |= (Lb[ks].w ^ (rtag));          \
            }                                                                    \
            if (__all((int)((err & 0xFFFFu) == 0u))) break;                      \
            if (++spins > 16384) break;                                          \
            __builtin_amdgcn_s_sleep(1);                                         \
            ISSUE_ALL(hb);                                                       \
        }                                                                        \
        __builtin_amdgcn_sched_barrier(0);                                       \
    }

// flag gate: all 16 same-wave writers posted >= rtag
#define FLAG_GATE(rtag)                                                          \
    {                                                                            \
        int spins = 0;                                                           \
        while (!__all((int)(load_flag(pollp) >= (u32)(rtag)))) {                 \
            if (++spins > 16384) break;                                          \
            __builtin_amdgcn_s_sleep(1);                                         \
        }                                                                        \
        __builtin_amdgcn_sched_barrier(0);                                       \
    }

// unpack tile ks: high halves of 8 tagged words -> bf16x8 A-fragment
#define UNPK(ks)                                                                 \
    {                                                                            \
        u32x4 v;                                                                 \
        v.x = __builtin_amdgcn_perm(La[ks].y, La[ks].x, 0x07060302u);            \
        v.y = __builtin_amdgcn_perm(La[ks].w, La[ks].z, 0x07060302u);            \
        v.z = __builtin_amdgcn_perm(Lb[ks].y, Lb[ks].x, 0x07060302u);            \
        v.w = __builtin_amdgcn_perm(Lb[ks].w, Lb[ks].z, 0x07060302u);            \
        ha[ks] = __builtin_bit_cast(bf16x8, v);                                  \
    }

// ---------------- weight packing (fragment layout, unchanged) ----------------
__global__ void pack_kernel(const float* __restrict__ eWih, const float* __restrict__ eWhh,
                            const float* __restrict__ dWih, const float* __restrict__ dWhh,
                            const float* __restrict__ linW,
                            bf16* __restrict__ encB, bf16* __restrict__ decB, bf16* __restrict__ linB) {
    int idx = blockIdx.x * 256 + threadIdx.x;  // 0 .. 819199
    if (idx < 786432) {
        int which = idx / 393216;          // 0 = enc, 1 = dec
        int id = idx % 393216;
        int cg = id / 24576;
        int rem = id % 24576;
        int ks = rem / 2048;
        int n = (rem / 512) & 3;
        int lane = (rem >> 3) & 63;
        int e = rem & 7;
        int k = ks * 32 + (lane >> 4) * 8 + e;
        int col = n * 256 + cg * 16 + (lane & 15);
        const float* Wih = which ? dWih : eWih;
        const float* Whh = which ? dWhh : eWhh;
        float v = (k < 128) ? Wih[col * 128 + k] : Whh[col * 256 + (k - 128)];
        (which ? decB : encB)[id] = (bf16)v;
    } else if (idx < 819200) {
        int i3 = idx - 786432;             // 0 .. 32767
        int ks = i3 >> 12;
        int n = (i3 >> 9) & 7;
        int lane = (i3 >> 3) & 63;
        int e = i3 & 7;
        int k = ks * 32 + (lane >> 4) * 8 + e;
        int col = n * 16 + (lane & 15);
        linB[i3] = (bf16)linW[col * 256 + k];
    }
}

// re-init h tags + flags every launch (replay safety; runs inside the graph)
__global__ void zero_kernel(unsigned* __restrict__ p) {
    int i = blockIdx.x * 256 + threadIdx.x;
    if (i < 65536) AT_STORE_DEV(&p[i], 0u);                 // buf0: h0=0, tag 0 (valid)
    else if (i < 131072) AT_STORE_DEV(&p[i], 0x0000FFFFu);  // buf1: sentinel tag
    else if (i < 131328) AT_STORE_DEV(&p[i], 0u);           // per-wave flags
}

// ---------------- main persistent kernel ----------------
__global__ __launch_bounds__(256, 1)
void lstm_main(const float* __restrict__ x,
               const float* __restrict__ eb_ih, const float* __restrict__ eb_hh,
               const float* __restrict__ db_ih, const float* __restrict__ db_hh,
               const float* __restrict__ lin_b,
               const bf16* __restrict__ encB, const bf16* __restrict__ decB,
               const bf16* __restrict__ linB,
               u32* __restrict__ hbuf32, u32* __restrict__ flags,
               float* __restrict__ out) {
    __shared__ bf16 Bg[24576];         // 48 KB gate-weight fragments (this cg)
    __shared__ bf16 Lw[32768];         // 64 KB lin_W fragments (decoder)
    __shared__ bf16 Pst[4 * 16 * 136]; // 17 KB pred staging, per-wave, pitch 136

    const int bid = blockIdx.x;
    const int rg = bid >> 4;           // row-group 0..3  (64 batch rows)
    const int cg = bid & 15;           // col-group 0..15 (16 hidden units)
    const int tid = threadIdx.x;
    const int w = tid >> 6;
    const int lane = tid & 63;
    const int l15 = lane & 15, l4 = lane >> 4;
    const int rbase = rg * 64 + w * 16;       // wave's 16 batch rows
    const int ucol = cg * 16 + l15;           // this lane's hidden unit
    const int arow = rbase + l15;             // A-fragment row this lane loads
    const int k0 = l4 * 8;                    // A-fragment k sub-offset
    const int prow = rbase + l4 * 4;          // epilogue row base

    // tagged h layout: hbuf[phase 65536][rt=16][row16=16][unit=256] (1 word/bf16)
    const int rt = rg * 4 + w;                           // this wave's row tile
    const int rd_off = rt * 4096 + l15 * 256 + l4 * 8;   // reader base (word)
    const int wr_off = rt * 4096 + (l4 * 4) * 256 + ucol;// writer base (word, +r*256)

    // per-wave flag chain: line of 16 words per rt
    u32* myflag = flags + rt * 16 + cg;
    const u32* pollp = flags + rt * 16 + l15;

    // load encoder gate weights into LDS
    {
        const f32x4* src = (const f32x4*)(encB + cg * 24576);
        f32x4* dst = (f32x4*)Bg;
        #pragma unroll
        for (int i = 0; i < 12; i++) dst[tid + 256 * i] = src[tid + 256 * i];
    }
    float bias_g[4];
    #pragma unroll
    for (int g = 0; g < 4; g++) bias_g[g] = eb_ih[g * 256 + ucol] + eb_hh[g * 256 + ucol];
    __syncthreads();

    float c[4] = {0.f, 0.f, 0.f, 0.f};
    const float* xrow = x + (size_t)arow * 512 * 128 + k0;  // x[arow][t][k0+..]

    // preload x fragments for t=0
    f32x4 xr[8];
    #pragma unroll
    for (int i = 0; i < 4; i++) {
        xr[2 * i]     = *(const f32x4*)(xrow + i * 32);
        xr[2 * i + 1] = *(const f32x4*)(xrow + i * 32 + 4);
    }

    // =================== encoder: 512 steps ===================
    for (int t = 0; t < 512; t++) {
        const u32* hb = hbuf32 + (t & 1) * 65536 + rd_off;
        u32* hw32 = hbuf32 + ((t + 1) & 1) * 65536;
        const u32 rtag = (u32)t;

        FLAG_GATE(rtag);                 // writers posted h_t (issued)

        u32x4 La[8], Lb[8];
        ISSUE_ALL(hb);

        f32x4 acc[4];
        #pragma unroll
        for (int n = 0; n < 4; n++) acc[n] = (f32x4){0.f, 0.f, 0.f, 0.f};

        // x part (K 0..127) from prefetched regs — overlaps h-load flight
        #pragma unroll
        for (int ks = 0; ks < 4; ks++) {
            f32x4 xa = xr[2 * ks], xb = xr[2 * ks + 1];
            bf16x8 a;
            a[0] = (bf16)xa[0]; a[1] = (bf16)xa[1]; a[2] = (bf16)xa[2]; a[3] = (bf16)xa[3];
            a[4] = (bf16)xb[0]; a[5] = (bf16)xb[1]; a[6] = (bf16)xb[2]; a[7] = (bf16)xb[3];
            #pragma unroll
            for (int n = 0; n < 4; n++) {
                bf16x8 b = *(const bf16x8*)&Bg[((ks * 4 + n) * 64 + lane) * 8];
                acc[n] = MFMA16(a, b, acc[n]);
            }
        }
        POLL_FRESH(hb, rtag);            // usually 0 retries (flag-gated)

        // x prefetch for t+1 NOW — hides under h-MFMA + epilogue
        int tn = t < 511 ? t + 1 : 511;
        #pragma unroll
        for (int i = 0; i < 4; i++) {
            xr[2 * i]     = *(const f32x4*)(xrow + (size_t)tn * 128 + i * 32);
            xr[2 * i + 1] = *(const f32x4*)(xrow + (size_t)tn * 128 + i * 32 + 4);
        }

        bf16x8 ha[8];
        #pragma unroll
        for (int ks = 0; ks < 8; ks++) {
            UNPK(ks);
            #pragma unroll
            for (int n = 0; n < 4; n++) {
                bf16x8 b = *(const bf16x8*)&Bg[(((ks + 4) * 4 + n) * 64 + lane) * 8];
                acc[n] = MFMA16(ha[ks], b, acc[n]);
            }
        }
        // epilogue: tagged fire-and-forget h stores, then fire-and-forget flag
        const u32 wtag = (u32)(t + 1);
        u32 tv[4];
        #pragma unroll
        for (int r = 0; r < 4; r++) {
            float gi = sigm(acc[0][r] + bias_g[0]);
            float gf = sigm(acc[1][r] + bias_g[1]);
            float gg = tanhfast(acc[2][r] + bias_g[2]);
            float go = sigm(acc[3][r] + bias_g[3]);
            c[r] = gf * c[r] + gi * gg;
            float h = go * tanhfast(c[r]);
            tv[r] = ((u32)__builtin_bit_cast(unsigned short, (bf16)h) << 16) | wtag;
        }
        u32* wb = hw32 + wr_off;
        GST1(wb, tv[0], "0");
        GST1(wb, tv[1], "1024");
        GST1(wb, tv[2], "2048");
        GST1(wb, tv[3], "3072");
        if (lane == 0) GST1(myflag, wtag, "0");
    }

    // =================== switch to decoder weights ===================
    __syncthreads();   // all 4 waves done with enc Bg
    {
        const f32x4* src = (const f32x4*)(decB + cg * 24576);
        f32x4* dst = (f32x4*)Bg;
        #pragma unroll
        for (int i = 0; i < 12; i++) dst[tid + 256 * i] = src[tid + 256 * i];
        const f32x4* s2 = (const f32x4*)linB;
        f32x4* d2 = (f32x4*)Lw;
        #pragma unroll
        for (int i = 0; i < 16; i++) d2[tid + 256 * i] = s2[tid + 256 * i];
    }
    float bias_d[4];
    #pragma unroll
    for (int g = 0; g < 4; g++) bias_d[g] = db_ih[g * 256 + ucol] + db_hh[g * 256 + ucol];
    float lbias[8];
    #pragma unroll
    for (int n = 0; n < 8; n++) lbias[n] = lin_b[n * 16 + l15];
    __syncthreads();

    const int ncg = cg >> 1;   // out columns this block writes: n == ncg, half == (cg&1)
    const int hsel = cg & 1;

    // =================== decoder: pred(k) then gates(k) ===================
    for (int k = 0; k < 512; k++) {
        const u32* hb = hbuf32 + (k & 1) * 65536 + rd_off;
        const u32 rtag = (u32)(512 + k);

        FLAG_GATE(rtag);

        u32x4 La[8], Lb[8];
        ISSUE_ALL(hb);
        POLL_FRESH(hb, rtag);
        bf16x8 ha[8];
        #pragma unroll
        for (int ks = 0; ks < 8; ks++) UNPK(ks);

        // pred = sigmoid(h @ lin_W^T + lin_b)  [64 x 128], redundant per block
        f32x4 pacc[8];
        #pragma unroll
        for (int n = 0; n < 8; n++) pacc[n] = (f32x4){0.f, 0.f, 0.f, 0.f};
        #pragma unroll
        for (int ks = 0; ks < 8; ks++) {
            #pragma unroll
            for (int n = 0; n < 8; n++) {
                bf16x8 b = *(const bf16x8*)&Lw[((ks * 8 + n) * 64 + lane) * 8];
                pacc[n] = MFMA16(ha[ks], b, pacc[n]);
            }
        }
        const int t_out = 511 - k;
        float* obase = out + (size_t)prow * 512 * 128 + (size_t)t_out * 128;
        bf16* pst_w = Pst + w * 2176;
        #pragma unroll
        for (int n = 0; n < 8; n++) {
            #pragma unroll
            for (int r = 0; r < 4; r++) {
                float p = sigm(pacc[n][r] + lbias[n]);
                pst_w[(l4 * 4 + r) * 136 + n * 16 + l15] = (bf16)p;
            }
        }
        if (k == 511) {   // last step: prediction only
            #pragma unroll
            for (int r = 0; r < 4; r++) {
                float p = sigm(pacc[ncg][r] + lbias[ncg]);
                if ((l15 >> 3) == hsel)
                    obase[(size_t)r * 512 * 128 + ncg * 16 + l15] = p;
            }
            break;
        }

        // gates = [pred | h] @ Wdec^T : h-part then pred-part from Pst
        f32x4 acc[4];
        #pragma unroll
        for (int n = 0; n < 4; n++) acc[n] = (f32x4){0.f, 0.f, 0.f, 0.f};
        #pragma unroll
        for (int ks = 0; ks < 8; ks++) {
            #pragma unroll
            for (int n = 0; n < 4; n++) {
                bf16x8 b = *(const bf16x8*)&Bg[(((ks + 4) * 4 + n) * 64 + lane) * 8];
                acc[n] = MFMA16(ha[ks], b, acc[n]);
            }
        }
        const bf16* pst_r = Pst + w * 2176 + l15 * 136 + k0;
        #pragma unroll
        for (int ks = 0; ks < 4; ks++) {
            bf16x8 a = *(const bf16x8*)(pst_r + ks * 32);
            #pragma unroll
            for (int n = 0; n < 4; n++) {
                bf16x8 b = *(const bf16x8*)&Bg[((ks * 4 + n) * 64 + lane) * 8];
                acc[n] = MFMA16(a, b, acc[n]);
            }
        }
        // epilogue: tagged h stores + flag (fire-and-forget), THEN out stores
        u32* hw32 = hbuf32 + ((k + 1) & 1) * 65536;
        const u32 wtag = (u32)(513 + k);
        u32 tv[4];
        #pragma unroll
        for (int r = 0; r < 4; r++) {
            float gi = sigm(acc[0][r] + bias_d[0]);
            float gf = sigm(acc[1][r] + bias_d[1]);
            float gg = tanhfast(acc[2][r] + bias_d[2]);
            float go = sigm(acc[3][r] + bias_d[3]);
            c[r] = gf * c[r] + gi * gg;
            float h = go * tanhfast(c[r]);
            tv[r] = ((u32)__builtin_bit_cast(unsigned short, (bf16)h) << 16) | wtag;
        }
        u32* wb = hw32 + wr_off;
        GST1(wb, tv[0], "0");
        GST1(wb, tv[1], "1024");
        GST1(wb, tv[2], "2048");
        GST1(wb, tv[3], "3072");
        if (lane == 0) GST1(myflag, wtag, "0");
        // deferred out stores (off the flag path)
        #pragma unroll
        for (int r = 0; r < 4; r++) {
            float p = sigm(pacc[ncg][r] + lbias[ncg]);
            if ((l15 >> 3) == hsel)
                obase[(size_t)r * 512 * 128 + ncg * 16 + l15] = p;
        }
    }
}

extern "C" void kernel_launch(void* const* d_in, const int* in_sizes, int n_in,
                              void* d_out, int out_size, void* d_ws, size_t ws_size,
                              hipStream_t stream) {
    const float* x    = (const float*)d_in[0];
    const float* eWih = (const float*)d_in[1];
    const float* eWhh = (const float*)d_in[2];
    const float* ebih = (const float*)d_in[3];
    const float* ebhh = (const float*)d_in[4];
    const float* dWih = (const float*)d_in[5];
    const float* dWhh = (const float*)d_in[6];
    const float* dbih = (const float*)d_in[7];
    const float* dbhh = (const float*)d_in[8];
    const float* linW = (const float*)d_in[9];
    const float* linb = (const float*)d_in[10];
    float* out = (float*)d_out;

    // workspace layout (~2.2 MB)
    bf16* encB = (bf16*)d_ws;            // 393216 bf16
    bf16* decB = encB + 393216;          // 393216 bf16
    bf16* linB = decB + 393216;          // 32768 bf16
    u32*  hbuf = (u32*)(linB + 32768);   // 2 x 16 tiles x 16 rows x 256 tagged words
    u32*  flags = hbuf + 131072;         // 16 rt-lines x 16 words

    hipLaunchKernelGGL(pack_kernel, dim3(3200), dim3(256), 0, stream,
                       eWih, eWhh, dWih, dWhh, linW, encB, decB, linB);
    hipLaunchKernelGGL(zero_kernel, dim3(513), dim3(256), 0, stream, hbuf);
    hipLaunchKernelGGL(lstm_main, dim3(64), dim3(256), 0, stream,
                       x, ebih, ebhh, dbih, dbhh, linb, encB, decB, linB, hbuf, flags, out);
}

// Round 9
// 5644.891 us; speedup vs baseline: 1.1229x; 1.0914x over previous
//
#include <hip/hip_runtime.h>

// B=256, T=512, I=128, H=256, 4H=1024
// 64 blocks = 4 row-groups x 16 col-groups. r4 protocol (untagged packed h, drain ->
// flag -> poll, all device-scope sc0 sc1) with PER-WAVE sync chains: wave w of block
// (rg,cg) syncs only with wave w of the 15 peer blocks (vmcnt is per-wave), so there
// are 16 independent chains and no in-loop __syncthreads. All in-loop VMEM is inline
// asm (compiler has no loads of its own to serialize). x-prefetch sits between h-wait
// and h-MFMA so its latency hides under compute + store-drain, not the poll.

typedef __bf16 bf16;
typedef bf16 bf16x8 __attribute__((ext_vector_type(8)));
typedef float f32x4 __attribute__((ext_vector_type(4)));
typedef unsigned u32;
typedef u32 u32x4 __attribute__((ext_vector_type(4)));

#define MFMA16(a, b, c) __builtin_amdgcn_mfma_f32_16x16x32_bf16((a), (b), (c), 0, 0, 0)
#define AT_STORE_DEV(p, v) __hip_atomic_store((p), (v), __ATOMIC_RELAXED, __HIP_MEMORY_SCOPE_AGENT)

__device__ __forceinline__ float sigm(float x) { return 1.0f / (1.0f + __expf(-x)); }
__device__ __forceinline__ float tanhfast(float x) { return 1.0f - 2.0f / (__expf(2.0f * x) + 1.0f); }

// device-coherent ops (L1+L2 bypass) — r4-proven paths
__device__ __forceinline__ u32x4 load_hx4(const u32* p) {
    u32x4 v;
    asm volatile("global_load_dwordx4 %0, %1, off sc0 sc1" : "=v"(v) : "v"(p));
    return v;
}
__device__ __forceinline__ void store_h(u32* p, u32 v) {
    asm volatile("global_store_dword %0, %1, off sc0 sc1" :: "v"(p), "v"(v) : "memory");
}
__device__ __forceinline__ u32 load_flag(const u32* p) {
    u32 v;
    asm volatile("global_load_dword %0, %1, off sc0 sc1\n\ts_waitcnt vmcnt(0)"
                 : "=v"(v) : "v"(p) : "memory");
    return v;
}
// plain cached VMEM as asm (keeps the compiler's vmcnt model empty in the loops)
__device__ __forceinline__ f32x4 load_x4a(const float* p) {
    f32x4 v;
    asm volatile("global_load_dwordx4 %0, %1, off" : "=v"(v) : "v"(p));
    return v;
}
__device__ __forceinline__ void store_f32a(float* p, float v) {
    asm volatile("global_store_dword %0, %1, off" :: "v"(p), "v"(v) : "memory");
}
#define DRAIN0() do { asm volatile("s_waitcnt vmcnt(0)" ::: "memory"); \
                      __builtin_amdgcn_sched_barrier(0); } while (0)

// flag gate: all 16 same-chain writers posted >= rtag (bounded -> fast wrong-answer)
#define FLAG_GATE(rtag)                                                          \
    {                                                                            \
        int spins = 0;                                                           \
        while (!__all((int)(load_flag(pollp) >= (u32)(rtag)))) {                 \
            if (++spins > (1 << 17)) break;                                      \
            __builtin_amdgcn_s_sleep(1);                                         \
        }                                                                        \
        __builtin_amdgcn_sched_barrier(0);                                       \
    }

// ---------------- weight packing (fragment layout, unchanged) ----------------
__global__ void pack_kernel(const float* __restrict__ eWih, const float* __restrict__ eWhh,
                            const float* __restrict__ dWih, const float* __restrict__ dWhh,
                            const float* __restrict__ linW,
                            bf16* __restrict__ encB, bf16* __restrict__ decB, bf16* __restrict__ linB) {
    int idx = blockIdx.x * 256 + threadIdx.x;  // 0 .. 819199
    if (idx < 786432) {
        int which = idx / 393216;          // 0 = enc, 1 = dec
        int id = idx % 393216;
        int cg = id / 24576;
        int rem = id % 24576;
        int ks = rem / 2048;
        int n = (rem / 512) & 3;
        int lane = (rem >> 3) & 63;
        int e = rem & 7;
        int k = ks * 32 + (lane >> 4) * 8 + e;
        int col = n * 256 + cg * 16 + (lane & 15);
        const float* Wih = which ? dWih : eWih;
        const float* Whh = which ? dWhh : eWhh;
        float v = (k < 128) ? Wih[col * 128 + k] : Whh[col * 256 + (k - 128)];
        (which ? decB : encB)[id] = (bf16)v;
    } else if (idx < 819200) {
        int i3 = idx - 786432;             // 0 .. 32767
        int ks = i3 >> 12;
        int n = (i3 >> 9) & 7;
        int lane = (i3 >> 3) & 63;
        int e = i3 & 7;
        int k = ks * 32 + (lane >> 4) * 8 + e;
        int col = n * 16 + (lane & 15);
        linB[i3] = (bf16)linW[col * 256 + k];
    }
}

__global__ void zero_kernel(unsigned* __restrict__ p) {
    int i = blockIdx.x * 256 + threadIdx.x;
    // h ping-pong (65536 words) + per-wave flags (256 words)
    if (i < 65792) AT_STORE_DEV(&p[i], 0u);
}

// ---------------- main persistent kernel ----------------
__global__ __launch_bounds__(256, 1)
void lstm_main(const float* __restrict__ x,
               const float* __restrict__ eb_ih, const float* __restrict__ eb_hh,
               const float* __restrict__ db_ih, const float* __restrict__ db_hh,
               const float* __restrict__ lin_b,
               const bf16* __restrict__ encB, const bf16* __restrict__ decB,
               const bf16* __restrict__ linB,
               u32* __restrict__ hbuf32, u32* __restrict__ flags,
               float* __restrict__ out) {
    __shared__ bf16 Bg[24576];         // 48 KB gate-weight fragments (this cg)
    __shared__ bf16 Lw[32768];         // 64 KB lin_W fragments (decoder)
    __shared__ bf16 Pst[4 * 16 * 136]; // 17 KB pred staging, per-wave, pitch 136

    const int bid = blockIdx.x;
    const int rg = bid >> 4;           // row-group 0..3  (64 batch rows)
    const int cg = bid & 15;           // col-group 0..15 (16 hidden units)
    const int tid = threadIdx.x;
    const int w = tid >> 6;
    const int lane = tid & 63;
    const int l15 = lane & 15, l4 = lane >> 4;
    const int rbase = rg * 64 + w * 16;       // wave's 16 batch rows
    const int ucol = cg * 16 + l15;           // this lane's hidden unit
    const int arow = rbase + l15;             // A-fragment row this lane loads
    const int k0 = l4 * 8;                    // A-fragment k sub-offset
    const int prow = rbase + l4 * 4;          // epilogue row base

    // h fragment layout: hbuf[phase][rt=16][ks=8][256 words]  (r4-proven)
    const int rt = rg * 4 + w;                // this wave's row tile (reads & writes)
    const int htile_w = (cg >> 1) * 256;      // writer's ks-tile
    const int hgrp = ((cg & 1) * 2 + (l15 >> 3)) * 16;
    const int widx = (l15 & 7) >> 1;

    // per-wave flag chain: line of 16 words per rt; chain = same (rg,w) across cg
    u32* myflag = flags + rt * 16 + cg;
    const u32* pollp = flags + rt * 16 + l15;

    // load encoder gate weights into LDS
    {
        const f32x4* src = (const f32x4*)(encB + cg * 24576);
        f32x4* dst = (f32x4*)Bg;
        #pragma unroll
        for (int i = 0; i < 12; i++) dst[tid + 256 * i] = src[tid + 256 * i];
    }
    float bias_g[4];
    #pragma unroll
    for (int g = 0; g < 4; g++) bias_g[g] = eb_ih[g * 256 + ucol] + eb_hh[g * 256 + ucol];
    __syncthreads();

    float c[4] = {0.f, 0.f, 0.f, 0.f};
    const float* xrow = x + (size_t)arow * 512 * 128 + k0;  // x[arow][t][k0+..]

    // preload x fragments for t=0 (asm; drained by first gate's vmcnt(0))
    f32x4 xr[8];
    #pragma unroll
    for (int i = 0; i < 4; i++) {
        xr[2 * i]     = load_x4a(xrow + i * 32);
        xr[2 * i + 1] = load_x4a(xrow + i * 32 + 4);
    }

    // =================== encoder: 512 steps ===================
    for (int t = 0; t < 512; t++) {
        const u32* hr32 = hbuf32 + (t & 1) * 32768;
        u32* hw32 = hbuf32 + ((t + 1) & 1) * 32768;

        FLAG_GATE(t);                  // same-chain writers posted h_t (and drains all)

        // issue 8 coalesced h-tile loads (only outstanding VMEM now)
        u32x4 hv[8];
        const u32* hb = hr32 + rt * 2048 + lane * 4;
        #pragma unroll
        for (int ks = 0; ks < 8; ks++) hv[ks] = load_hx4(hb + ks * 256);

        f32x4 acc[4];
        #pragma unroll
        for (int n = 0; n < 4; n++) acc[n] = (f32x4){0.f, 0.f, 0.f, 0.f};

        // x part (K 0..127) from prefetched regs — overlaps h-load flight
        #pragma unroll
        for (int ks = 0; ks < 4; ks++) {
            f32x4 xa = xr[2 * ks], xb = xr[2 * ks + 1];
            bf16x8 a;
            a[0] = (bf16)xa[0]; a[1] = (bf16)xa[1]; a[2] = (bf16)xa[2]; a[3] = (bf16)xa[3];
            a[4] = (bf16)xb[0]; a[5] = (bf16)xb[1]; a[6] = (bf16)xb[2]; a[7] = (bf16)xb[3];
            #pragma unroll
            for (int n = 0; n < 4; n++) {
                bf16x8 b = *(const bf16x8*)&Bg[((ks * 4 + n) * 64 + lane) * 8];
                acc[n] = MFMA16(a, b, acc[n]);
            }
        }
        DRAIN0();                      // h fragments resident

        // x prefetch for t+1 NOW — hides under h-MFMA + epilogue + store-drain
        int tn = t < 511 ? t + 1 : 511;
        #pragma unroll
        for (int i = 0; i < 4; i++) {
            xr[2 * i]     = load_x4a(xrow + (size_t)tn * 128 + i * 32);
            xr[2 * i + 1] = load_x4a(xrow + (size_t)tn * 128 + i * 32 + 4);
        }

        // h part (K 128..383)
        #pragma unroll
        for (int ks = 0; ks < 8; ks++) {
            bf16x8 a = __builtin_bit_cast(bf16x8, hv[ks]);
            #pragma unroll
            for (int n = 0; n < 4; n++) {
                bf16x8 b = *(const bf16x8*)&Bg[(((ks + 4) * 4 + n) * 64 + lane) * 8];
                acc[n] = MFMA16(a, b, acc[n]);
            }
        }
        // epilogue: lane owns rows prow+r, unit ucol; packed fragment-layout h stores
        #pragma unroll
        for (int r = 0; r < 4; r++) {
            float gi = sigm(acc[0][r] + bias_g[0]);
            float gf = sigm(acc[1][r] + bias_g[1]);
            float gg = tanhfast(acc[2][r] + bias_g[2]);
            float go = sigm(acc[3][r] + bias_g[3]);
            c[r] = gf * c[r] + gi * gg;
            float h = go * tanhfast(c[r]);
            unsigned hvv = (unsigned)__builtin_bit_cast(unsigned short, (bf16)h);
            unsigned hp = __shfl_xor(hvv, 1);
            if (!(lane & 1))
                store_h(&hw32[rt * 2048 + htile_w + (hgrp + l4 * 4 + r) * 4 + widx],
                        hvv | (hp << 16));
        }
        // drain own stores (+x prefetch, overlapped) -> post own flag
        DRAIN0();
        if (lane == 0) store_h(myflag, (u32)(t + 1));
    }

    // =================== switch to decoder weights ===================
    __syncthreads();   // join 4 waves (each validated its chain at t=511) -> Bg free
    {
        const f32x4* src = (const f32x4*)(decB + cg * 24576);
        f32x4* dst = (f32x4*)Bg;
        #pragma unroll
        for (int i = 0; i < 12; i++) dst[tid + 256 * i] = src[tid + 256 * i];
        const f32x4* s2 = (const f32x4*)linB;
        f32x4* d2 = (f32x4*)Lw;
        #pragma unroll
        for (int i = 0; i < 16; i++) d2[tid + 256 * i] = s2[tid + 256 * i];
    }
    float bias_d[4];
    #pragma unroll
    for (int g = 0; g < 4; g++) bias_d[g] = db_ih[g * 256 + ucol] + db_hh[g * 256 + ucol];
    float lbias[8];
    #pragma unroll
    for (int n = 0; n < 8; n++) lbias[n] = lin_b[n * 16 + l15];
    __syncthreads();

    const int ncg = cg >> 1;   // out columns this block writes: n == ncg, half == (cg&1)
    const int hsel = cg & 1;

    // =================== decoder: pred(k) then gates(k) ===================
    for (int k = 0; k < 512; k++) {
        const u32* hr32 = hbuf32 + (k & 1) * 32768;
        const u32 rtag = (u32)(512 + k);

        FLAG_GATE(rtag);

        u32x4 hv[8];
        const u32* hb = hr32 + rt * 2048 + lane * 4;
        #pragma unroll
        for (int ks = 0; ks < 8; ks++) hv[ks] = load_hx4(hb + ks * 256);
        DRAIN0();
        bf16x8 ha[8];
        #pragma unroll
        for (int ks = 0; ks < 8; ks++) ha[ks] = __builtin_bit_cast(bf16x8, hv[ks]);

        // pred = sigmoid(h @ lin_W^T + lin_b)  [64 x 128], redundant per block
        f32x4 pacc[8];
        #pragma unroll
        for (int n = 0; n < 8; n++) pacc[n] = (f32x4){0.f, 0.f, 0.f, 0.f};
        #pragma unroll
        for (int ks = 0; ks < 8; ks++) {
            #pragma unroll
            for (int n = 0; n < 8; n++) {
                bf16x8 b = *(const bf16x8*)&Lw[((ks * 8 + n) * 64 + lane) * 8];
                pacc[n] = MFMA16(ha[ks], b, pacc[n]);
            }
        }
        const int t_out = 511 - k;
        float* obase = out + (size_t)prow * 512 * 128 + (size_t)t_out * 128;
        bf16* pst_w = Pst + w * 2176;
        #pragma unroll
        for (int n = 0; n < 8; n++) {
            #pragma unroll
            for (int r = 0; r < 4; r++) {
                float p = sigm(pacc[n][r] + lbias[n]);
                pst_w[(l4 * 4 + r) * 136 + n * 16 + l15] = (bf16)p;
            }
        }
        if (k == 511) {   // last step: prediction only
            #pragma unroll
            for (int r = 0; r < 4; r++) {
                float p = sigm(pacc[ncg][r] + lbias[ncg]);
                if ((l15 >> 3) == hsel)
                    store_f32a(&obase[(size_t)r * 512 * 128 + ncg * 16 + l15], p);
            }
            break;
        }

        // gates = [pred | h] @ Wdec^T : h-part, then pred-part from Pst (same wave)
        f32x4 acc[4];
        #pragma unroll
        for (int n = 0; n < 4; n++) acc[n] = (f32x4){0.f, 0.f, 0.f, 0.f};
        #pragma unroll
        for (int ks = 0; ks < 8; ks++) {
            #pragma unroll
            for (int n = 0; n < 4; n++) {
                bf16x8 b = *(const bf16x8*)&Bg[(((ks + 4) * 4 + n) * 64 + lane) * 8];
                acc[n] = MFMA16(ha[ks], b, acc[n]);
            }
        }
        const bf16* pst_r = Pst + w * 2176 + l15 * 136 + k0;
        #pragma unroll
        for (int ks = 0; ks < 4; ks++) {
            bf16x8 a = *(const bf16x8*)(pst_r + ks * 32);
            #pragma unroll
            for (int n = 0; n < 4; n++) {
                bf16x8 b = *(const bf16x8*)&Bg[((ks * 4 + n) * 64 + lane) * 8];
                acc[n] = MFMA16(a, b, acc[n]);
            }
        }
        // h epilogue: packed stores -> drain -> flag -> deferred out stores
        u32* hw32 = hbuf32 + ((k + 1) & 1) * 32768;
        #pragma unroll
        for (int r = 0; r < 4; r++) {
            float gi = sigm(acc[0][r] + bias_d[0]);
            float gf = sigm(acc[1][r] + bias_d[1]);
            float gg = tanhfast(acc[2][r] + bias_d[2]);
            float go = sigm(acc[3][r] + bias_d[3]);
            c[r] = gf * c[r] + gi * gg;
            float h = go * tanhfast(c[r]);
            unsigned hvv = (unsigned)__builtin_bit_cast(unsigned short, (bf16)h);
            unsigned hp = __shfl_xor(hvv, 1);
            if (!(lane & 1))
                store_h(&hw32[rt * 2048 + htile_w + (hgrp + l4 * 4 + r) * 4 + widx],
                        hvv | (hp << 16));
        }
        DRAIN0();
        if (lane == 0) store_h(myflag, (u32)(rtag + 1));
        // out stores off the flag path; drained inside next gate's vmcnt(0)
        #pragma unroll
        for (int r = 0; r < 4; r++) {
            float p = sigm(pacc[ncg][r] + lbias[ncg]);
            if ((l15 >> 3) == hsel)
                store_f32a(&obase[(size_t)r * 512 * 128 + ncg * 16 + l15], p);
        }
    }
}

extern "C" void kernel_launch(void* const* d_in, const int* in_sizes, int n_in,
                              void* d_out, int out_size, void* d_ws, size_t ws_size,
                              hipStream_t stream) {
    const float* x    = (const float*)d_in[0];
    const float* eWih = (const float*)d_in[1];
    const float* eWhh = (const float*)d_in[2];
    const float* ebih = (const float*)d_in[3];
    const float* ebhh = (const float*)d_in[4];
    const float* dWih = (const float*)d_in[5];
    const float* dWhh = (const float*)d_in[6];
    const float* dbih = (const float*)d_in[7];
    const float* dbhh = (const float*)d_in[8];
    const float* linW = (const float*)d_in[9];
    const float* linb = (const float*)d_in[10];
    float* out = (float*)d_out;

    // workspace layout (~1.9 MB)
    bf16* encB = (bf16*)d_ws;            // 393216 bf16
    bf16* decB = encB + 393216;          // 393216 bf16
    bf16* linB = decB + 393216;          // 32768 bf16
    u32*  hbuf = (u32*)(linB + 32768);   // 2 x 16 tiles x 8 ks x 256 u32 (fragment layout)
    u32*  flags = hbuf + 65536;          // 16 rt-lines x 16 words

    hipLaunchKernelGGL(pack_kernel, dim3(3200), dim3(256), 0, stream,
                       eWih, eWhh, dWih, dWhh, linW, encB, decB, linB);
    hipLaunchKernelGGL(zero_kernel, dim3(257), dim3(256), 0, stream, hbuf);
    hipLaunchKernelGGL(lstm_main, dim3(64), dim3(256), 0, stream,
                       x, ebih, ebhh, dbih, dbhh, linb, encB, decB, linB, hbuf, flags, out);
}

// Round 10
// 4792.880 us; speedup vs baseline: 1.3226x; 1.1778x over previous
//
#include <hip/hip_runtime.h>

// B=256, T=512, I=128, H=256, 4H=1024
// 64 workers = 4 row-groups (rg = XCC_ID) x 16 col-groups. Dual-protocol kernel:
//   bootstrap (device-scope, r4-proven ops): claim (rg,cg); canary-test whether
//   plain-store -> sc0-load is coherent within the XCD's L2; vote per rg.
//   LOCAL  : h/flag stores plain (dirty in shared L2), loads sc0-only (L1 bypass).
//   DEVICE : exact r4 protocol (sc0 sc1 everywhere) — proven 4865 us.
// Loop structure is byte-identical to round-4's passing kernel; only the cache-scope
// of the h/flag ops differs by template. All polls capped -> fail-fast, never hang.
// Replay safety: kernel-boundary device release/acquire is empirically proven by r4
// (plain-store pack_kernel -> plain-load lstm_main across XCDs, 50+ replays).

typedef __bf16 bf16;
typedef bf16 bf16x8 __attribute__((ext_vector_type(8)));
typedef float f32x4 __attribute__((ext_vector_type(4)));
typedef unsigned u32;
typedef u32 u32x4 __attribute__((ext_vector_type(4)));

#define MFMA16(a, b, c) __builtin_amdgcn_mfma_f32_16x16x32_bf16((a), (b), (c), 0, 0, 0)
#define AT_STORE_DEV(p, v) __hip_atomic_store((p), (v), __ATOMIC_RELAXED, __HIP_MEMORY_SCOPE_AGENT)

__device__ __forceinline__ float sigm(float x) { return 1.0f / (1.0f + __expf(-x)); }
__device__ __forceinline__ float tanhfast(float x) { return 1.0f - 2.0f / (__expf(2.0f * x) + 1.0f); }

// ---- steady-state ops, templated on locality ----
template<bool LOC> __device__ __forceinline__ u32x4 ld_h4(const u32* p) {
    u32x4 v;
    if constexpr (LOC) asm volatile("global_load_dwordx4 %0, %1, off sc0" : "=v"(v) : "v"(p));
    else               asm volatile("global_load_dwordx4 %0, %1, off sc0 sc1" : "=v"(v) : "v"(p));
    return v;
}
template<bool LOC> __device__ __forceinline__ void st_h(u32* p, u32 v) {
    if constexpr (LOC) asm volatile("global_store_dword %0, %1, off" :: "v"(p), "v"(v) : "memory");
    else               asm volatile("global_store_dword %0, %1, off sc0 sc1" :: "v"(p), "v"(v) : "memory");
}
template<bool LOC> __device__ __forceinline__ u32 ld_flag(const u32* p) {
    u32 v;
    if constexpr (LOC)
        asm volatile("global_load_dword %0, %1, off sc0\n\ts_waitcnt vmcnt(0)"
                     : "=v"(v) : "v"(p) : "memory");
    else
        asm volatile("global_load_dword %0, %1, off sc0 sc1\n\ts_waitcnt vmcnt(0)"
                     : "=v"(v) : "v"(p) : "memory");
    return v;
}
// ---- bootstrap ops (always device-scope / plain, r4-proven) ----
__device__ __forceinline__ void st_dev(u32* p, u32 v) {
    asm volatile("global_store_dword %0, %1, off sc0 sc1" :: "v"(p), "v"(v) : "memory");
}
__device__ __forceinline__ u32 ld_dev(const u32* p) {
    u32 v;
    asm volatile("global_load_dword %0, %1, off sc0 sc1\n\ts_waitcnt vmcnt(0)"
                 : "=v"(v) : "v"(p) : "memory");
    return v;
}
__device__ __forceinline__ void st_plain(u32* p, u32 v) {
    asm volatile("global_store_dword %0, %1, off" :: "v"(p), "v"(v) : "memory");
}
__device__ __forceinline__ u32 ld_sc0(const u32* p) {
    u32 v;
    asm volatile("global_load_dword %0, %1, off sc0\n\ts_waitcnt vmcnt(0)"
                 : "=v"(v) : "v"(p) : "memory");
    return v;
}

// ---------------- weight packing (fragment layout, unchanged) ----------------
__global__ void pack_kernel(const float* __restrict__ eWih, const float* __restrict__ eWhh,
                            const float* __restrict__ dWih, const float* __restrict__ dWhh,
                            const float* __restrict__ linW,
                            bf16* __restrict__ encB, bf16* __restrict__ decB, bf16* __restrict__ linB) {
    int idx = blockIdx.x * 256 + threadIdx.x;  // 0 .. 819199
    if (idx < 786432) {
        int which = idx / 393216;          // 0 = enc, 1 = dec
        int id = idx % 393216;
        int cg = id / 24576;
        int rem = id % 24576;
        int ks = rem / 2048;
        int n = (rem / 512) & 3;
        int lane = (rem >> 3) & 63;
        int e = rem & 7;
        int k = ks * 32 + (lane >> 4) * 8 + e;
        int col = n * 256 + cg * 16 + (lane & 15);
        const float* Wih = which ? dWih : eWih;
        const float* Whh = which ? dWhh : eWhh;
        float v = (k < 128) ? Wih[col * 128 + k] : Whh[col * 256 + (k - 128)];
        (which ? decB : encB)[id] = (bf16)v;
    } else if (idx < 819200) {
        int i3 = idx - 786432;             // 0 .. 32767
        int ks = i3 >> 12;
        int n = (i3 >> 9) & 7;
        int lane = (i3 >> 3) & 63;
        int e = i3 & 7;
        int k = ks * 32 + (lane >> 4) * 8 + e;
        int col = n * 16 + (lane & 15);
        linB[i3] = (bf16)linW[col * 256 + k];
    }
}

__global__ void zero_kernel(unsigned* __restrict__ p) {
    int i = blockIdx.x * 256 + threadIdx.x;
    // hbuf(65536) + flags(256) + xslot(8) + boot(256) + canary(256) = 66312 words
    if (i < 66312) AT_STORE_DEV(&p[i], 0u);
}

// ---------------- the steady-state chains (r4 loop, verbatim structure) ----------------
template<bool LOC>
__device__ void run_chains(int rg, int cg, int tid,
                           const float* __restrict__ x,
                           const float* __restrict__ eb_ih, const float* __restrict__ eb_hh,
                           const float* __restrict__ db_ih, const float* __restrict__ db_hh,
                           const float* __restrict__ lin_b,
                           const bf16* __restrict__ encB, const bf16* __restrict__ decB,
                           const bf16* __restrict__ linB,
                           u32* __restrict__ hbuf32, u32* __restrict__ flags,
                           float* __restrict__ out,
                           bf16* Bg, bf16* Lw, bf16* Pst) {
    const int w = tid >> 6;
    const int lane = tid & 63;
    const int l15 = lane & 15, l4 = lane >> 4;
    const int rbase = rg * 64 + w * 16;
    const int ucol = cg * 16 + l15;
    const int arow = rbase + l15;
    const int k0 = l4 * 8;
    const int prow = rbase + l4 * 4;

    // h fragment layout: hbuf[phase][rt=16][ks=8][256 words]
    const int rt = rg * 4 + w;
    const int htile_w = (cg >> 1) * 256;
    const int hgrp = ((cg & 1) * 2 + (l15 >> 3)) * 16;
    const int widx = (l15 & 7) >> 1;

    // load encoder gate weights into LDS
    {
        const f32x4* src = (const f32x4*)(encB + cg * 24576);
        f32x4* dst = (f32x4*)Bg;
        #pragma unroll
        for (int i = 0; i < 12; i++) dst[tid + 256 * i] = src[tid + 256 * i];
    }
    float bias_g[4];
    #pragma unroll
    for (int g = 0; g < 4; g++) bias_g[g] = eb_ih[g * 256 + ucol] + eb_hh[g * 256 + ucol];
    __syncthreads();

    u32* myflag = flags + rg * 64 + cg;
    const u32* pollp = flags + rg * 64 + l15;
    u32 stepno = 0;
    float c[4] = {0.f, 0.f, 0.f, 0.f};

    const float* xrow = x + (size_t)arow * 512 * 128 + k0;

    f32x4 xr[8];
    #pragma unroll
    for (int i = 0; i < 4; i++) {
        xr[2 * i]     = *(const f32x4*)(xrow + i * 32);
        xr[2 * i + 1] = *(const f32x4*)(xrow + i * 32 + 4);
    }

    // =================== encoder: 512 steps ===================
    for (int t = 0; t < 512; t++) {
        const u32* hr32 = hbuf32 + (t & 1) * 32768;
        u32* hw32 = hbuf32 + ((t + 1) & 1) * 32768;

        u32x4 hv[8];
        const u32* hb = hr32 + rt * 2048 + lane * 4;
        #pragma unroll
        for (int ks = 0; ks < 8; ks++) hv[ks] = ld_h4<LOC>(hb + ks * 256);

        f32x4 acc[4];
        #pragma unroll
        for (int n = 0; n < 4; n++) acc[n] = (f32x4){0.f, 0.f, 0.f, 0.f};

        #pragma unroll
        for (int ks = 0; ks < 4; ks++) {
            f32x4 xa = xr[2 * ks], xb = xr[2 * ks + 1];
            bf16x8 a;
            a[0] = (bf16)xa[0]; a[1] = (bf16)xa[1]; a[2] = (bf16)xa[2]; a[3] = (bf16)xa[3];
            a[4] = (bf16)xb[0]; a[5] = (bf16)xb[1]; a[6] = (bf16)xb[2]; a[7] = (bf16)xb[3];
            #pragma unroll
            for (int n = 0; n < 4; n++) {
                bf16x8 b = *(const bf16x8*)&Bg[((ks * 4 + n) * 64 + lane) * 8];
                acc[n] = MFMA16(a, b, acc[n]);
            }
        }
        asm volatile("s_waitcnt vmcnt(0)" ::: "memory");
        __builtin_amdgcn_sched_barrier(0);
        #pragma unroll
        for (int ks = 0; ks < 8; ks++) {
            bf16x8 a = __builtin_bit_cast(bf16x8, hv[ks]);
            #pragma unroll
            for (int n = 0; n < 4; n++) {
                bf16x8 b = *(const bf16x8*)&Bg[(((ks + 4) * 4 + n) * 64 + lane) * 8];
                acc[n] = MFMA16(a, b, acc[n]);
            }
        }
        #pragma unroll
        for (int r = 0; r < 4; r++) {
            float gi = sigm(acc[0][r] + bias_g[0]);
            float gf = sigm(acc[1][r] + bias_g[1]);
            float gg = tanhfast(acc[2][r] + bias_g[2]);
            float go = sigm(acc[3][r] + bias_g[3]);
            c[r] = gf * c[r] + gi * gg;
            float h = go * tanhfast(c[r]);
            unsigned hvv = (unsigned)__builtin_bit_cast(unsigned short, (bf16)h);
            unsigned hp = __shfl_xor(hvv, 1);
            if (!(lane & 1))
                st_h<LOC>(&hw32[rt * 2048 + htile_w + (hgrp + l4 * 4 + r) * 4 + widx],
                          hvv | (hp << 16));
        }
        // barrier: drain (syncthreads) -> post flag -> prefetch x -> wide poll
        stepno++;
        __syncthreads();
        if (tid == 0) st_h<LOC>(myflag, stepno);
        int tn = t < 511 ? t + 1 : 511;
        #pragma unroll
        for (int i = 0; i < 4; i++) {
            xr[2 * i]     = *(const f32x4*)(xrow + (size_t)tn * 128 + i * 32);
            xr[2 * i + 1] = *(const f32x4*)(xrow + (size_t)tn * 128 + i * 32 + 4);
        }
        {
            int sp = 0;
            while (!__all((int)(ld_flag<LOC>(pollp) >= stepno))) {
                if (++sp > 8192) break;
                __builtin_amdgcn_s_sleep(1);
            }
        }
    }

    // =================== switch to decoder weights ===================
    {
        const f32x4* src = (const f32x4*)(decB + cg * 24576);
        f32x4* dst = (f32x4*)Bg;
        #pragma unroll
        for (int i = 0; i < 12; i++) dst[tid + 256 * i] = src[tid + 256 * i];
        const f32x4* s2 = (const f32x4*)linB;
        f32x4* d2 = (f32x4*)Lw;
        #pragma unroll
        for (int i = 0; i < 16; i++) d2[tid + 256 * i] = s2[tid + 256 * i];
    }
    float bias_d[4];
    #pragma unroll
    for (int g = 0; g < 4; g++) bias_d[g] = db_ih[g * 256 + ucol] + db_hh[g * 256 + ucol];
    float lbias[8];
    #pragma unroll
    for (int n = 0; n < 8; n++) lbias[n] = lin_b[n * 16 + l15];
    __syncthreads();

    const int ncg = cg >> 1;
    const int hsel = cg & 1;

    // =================== decoder: pred(k) then gates(k) ===================
    for (int k = 0; k < 512; k++) {
        const u32* hr32 = hbuf32 + (k & 1) * 32768;

        u32x4 hv[8];
        const u32* hb = hr32 + rt * 2048 + lane * 4;
        #pragma unroll
        for (int ks = 0; ks < 8; ks++) hv[ks] = ld_h4<LOC>(hb + ks * 256);
        asm volatile("s_waitcnt vmcnt(0)" ::: "memory");
        __builtin_amdgcn_sched_barrier(0);
        bf16x8 ha[8];
        #pragma unroll
        for (int ks = 0; ks < 8; ks++) ha[ks] = __builtin_bit_cast(bf16x8, hv[ks]);

        f32x4 pacc[8];
        #pragma unroll
        for (int n = 0; n < 8; n++) pacc[n] = (f32x4){0.f, 0.f, 0.f, 0.f};
        #pragma unroll
        for (int ks = 0; ks < 8; ks++) {
            #pragma unroll
            for (int n = 0; n < 8; n++) {
                bf16x8 b = *(const bf16x8*)&Lw[((ks * 8 + n) * 64 + lane) * 8];
                pacc[n] = MFMA16(ha[ks], b, pacc[n]);
            }
        }
        const int t_out = 511 - k;
        float* obase = out + (size_t)prow * 512 * 128 + (size_t)t_out * 128;
        bf16* pst_w = Pst + w * 2176;
        #pragma unroll
        for (int n = 0; n < 8; n++) {
            #pragma unroll
            for (int r = 0; r < 4; r++) {
                float p = sigm(pacc[n][r] + lbias[n]);
                pst_w[(l4 * 4 + r) * 136 + n * 16 + l15] = (bf16)p;
                if (n == ncg && (l15 >> 3) == hsel)
                    obase[(size_t)r * 512 * 128 + n * 16 + l15] = p;
            }
        }
        if (k == 511) break;

        f32x4 acc[4];
        #pragma unroll
        for (int n = 0; n < 4; n++) acc[n] = (f32x4){0.f, 0.f, 0.f, 0.f};
        #pragma unroll
        for (int ks = 0; ks < 8; ks++) {
            #pragma unroll
            for (int n = 0; n < 4; n++) {
                bf16x8 b = *(const bf16x8*)&Bg[(((ks + 4) * 4 + n) * 64 + lane) * 8];
                acc[n] = MFMA16(ha[ks], b, acc[n]);
            }
        }
        const bf16* pst_r = Pst + w * 2176 + l15 * 136 + k0;
        #pragma unroll
        for (int ks = 0; ks < 4; ks++) {
            bf16x8 a = *(const bf16x8*)(pst_r + ks * 32);
            #pragma unroll
            for (int n = 0; n < 4; n++) {
                bf16x8 b = *(const bf16x8*)&Bg[((ks * 4 + n) * 64 + lane) * 8];
                acc[n] = MFMA16(a, b, acc[n]);
            }
        }
        u32* hw32 = hbuf32 + ((k + 1) & 1) * 32768;
        #pragma unroll
        for (int r = 0; r < 4; r++) {
            float gi = sigm(acc[0][r] + bias_d[0]);
            float gf = sigm(acc[1][r] + bias_d[1]);
            float gg = tanhfast(acc[2][r] + bias_d[2]);
            float go = sigm(acc[3][r] + bias_d[3]);
            c[r] = gf * c[r] + gi * gg;
            float h = go * tanhfast(c[r]);
            unsigned hvv = (unsigned)__builtin_bit_cast(unsigned short, (bf16)h);
            unsigned hp = __shfl_xor(hvv, 1);
            if (!(lane & 1))
                st_h<LOC>(&hw32[rt * 2048 + htile_w + (hgrp + l4 * 4 + r) * 4 + widx],
                          hvv | (hp << 16));
        }
        stepno++;
        __syncthreads();
        if (tid == 0) st_h<LOC>(myflag, stepno);
        {
            int sp = 0;
            while (!__all((int)(ld_flag<LOC>(pollp) >= stepno))) {
                if (++sp > 8192) break;
                __builtin_amdgcn_s_sleep(1);
            }
        }
    }
}

// ---------------- main persistent kernel ----------------
// ws word layout after hbuf: flags(256) | xslot(8) | boot(256) | canary(256)
__global__ __launch_bounds__(256, 1)
void lstm_main(const float* __restrict__ x,
               const float* __restrict__ eb_ih, const float* __restrict__ eb_hh,
               const float* __restrict__ db_ih, const float* __restrict__ db_hh,
               const float* __restrict__ lin_b,
               const bf16* __restrict__ encB, const bf16* __restrict__ decB,
               const bf16* __restrict__ linB,
               u32* __restrict__ hbuf32, u32* __restrict__ flags,
               float* __restrict__ out) {
    __shared__ bf16 Bg[24576];
    __shared__ bf16 Lw[32768];
    __shared__ bf16 Pst[4 * 16 * 136];
    __shared__ int s_role[2];

    const int tid = threadIdx.x;
    u32* xslot  = flags + 256;
    u32* boot   = flags + 264;
    u32* canary = flags + 520;

    // ---- claim (rg = XCC_ID, cg = slot) ----
    if (tid == 0) {
        u32 xcc;
        asm("s_getreg_b32 %0, hwreg(HW_REG_XCC_ID)" : "=s"(xcc));
        xcc &= 7;
        u32 slot = __hip_atomic_fetch_add(&xslot[xcc], 1u,
                                          __ATOMIC_RELAXED, __HIP_MEMORY_SCOPE_AGENT);
        s_role[0] = (int)xcc;
        s_role[1] = (int)slot;
    }
    __syncthreads();
    const int rg = s_role[0];
    const int cg = s_role[1];
    if (rg >= 4 || cg >= 16) return;   // not a worker

    // ---- canary: does plain-store -> sc0-load cohere within this XCD's L2? ----
    if (tid == 0) {
        st_plain(&canary[rg * 64 + cg], 1u);
        const u32* pc = &canary[rg * 64 + ((cg + 1) & 15)];
        u32 ok = 0;
        for (int i = 0; i < 4096; i++) {
            if (ld_sc0(pc) == 1u) { ok = 1; break; }
            __builtin_amdgcn_s_sleep(1);
        }
        st_dev(&boot[rg * 64 + cg], ok ? 2u : 1u);   // 2 = local-ok, 1 = fail
    }
    __syncthreads();

    // ---- vote (device-scope, bounded): all 16 posted; LOCAL iff all == 2 ----
    const int l15v = tid & 15;
    u32 myv = 0;
    {
        int sp = 0;
        for (;;) {
            myv = ld_dev(&boot[rg * 64 + l15v]);
            if (__all((int)(myv >= 1u))) break;
            if (++sp > (1 << 16)) break;
            __builtin_amdgcn_s_sleep(2);
        }
    }
    const bool local = __all((int)(myv == 2u));

    if (local)
        run_chains<true >(rg, cg, tid, x, eb_ih, eb_hh, db_ih, db_hh, lin_b,
                          encB, decB, linB, hbuf32, flags, out, Bg, Lw, Pst);
    else
        run_chains<false>(rg, cg, tid, x, eb_ih, eb_hh, db_ih, db_hh, lin_b,
                          encB, decB, linB, hbuf32, flags, out, Bg, Lw, Pst);
}

extern "C" void kernel_launch(void* const* d_in, const int* in_sizes, int n_in,
                              void* d_out, int out_size, void* d_ws, size_t ws_size,
                              hipStream_t stream) {
    const float* x    = (const float*)d_in[0];
    const float* eWih = (const float*)d_in[1];
    const float* eWhh = (const float*)d_in[2];
    const float* ebih = (const float*)d_in[3];
    const float* ebhh = (const float*)d_in[4];
    const float* dWih = (const float*)d_in[5];
    const float* dWhh = (const float*)d_in[6];
    const float* dbih = (const float*)d_in[7];
    const float* dbhh = (const float*)d_in[8];
    const float* linW = (const float*)d_in[9];
    const float* linb = (const float*)d_in[10];
    float* out = (float*)d_out;

    // workspace layout (~1.9 MB)
    bf16* encB = (bf16*)d_ws;            // 393216 bf16
    bf16* decB = encB + 393216;          // 393216 bf16
    bf16* linB = decB + 393216;          // 32768 bf16
    u32*  hbuf = (u32*)(linB + 32768);   // 2 x 16 tiles x 8 ks x 256 u32 (fragment layout)
    u32*  flags = hbuf + 65536;          // flags(256)+xslot(8)+boot(256)+canary(256)

    hipLaunchKernelGGL(pack_kernel, dim3(3200), dim3(256), 0, stream,
                       eWih, eWhh, dWih, dWhh, linW, encB, decB, linB);
    hipLaunchKernelGGL(zero_kernel, dim3(260), dim3(256), 0, stream, hbuf);
    hipLaunchKernelGGL(lstm_main, dim3(256), dim3(256), 0, stream,
                       x, ebih, ebhh, dbih, dbhh, linb, encB, decB, linB, hbuf, flags, out);
}